// Round 7
// baseline (271.663 us; speedup 1.0000x reference)
//
#include <hip/hip_runtime.h>
#include <stdint.h>

// ScoreMatching: B=2048, D=64, H=512.
// out[b] = 0.5*||s_b||^2 + tr(W4 M3 W3 M2 W2 M1 W1)_b
// div_b = sum_{i,d} m2[i] * C[i,d] * G[i,d]
//   C = W2 @ (M1 .* W1)      [512 x 64]   A-frag = W2 rows,  B-frag = masked W1T rows
//   G = W3^T @ (M3 .* W4^T)  [512 x 64]   A-frag = W3T rows, B-frag = masked W4 rows
// R11 changes:
//  - div v6: R6 model: LDS return path is the cap (221K cyc/CU of b128 reads
//    vs 159K MFMA; MfmaUtil 41% fits). B1/B4 are 128KB, L1/L2-hot, identical
//    addresses across waves/blocks -> read B-frags via global_load_dwordx4
//    into regs (reload in-place right after the masked bf16 copy, a full MFMA
//    cluster ahead of use). Only A staged in LDS (1 slot/wave/kc). LDS reads
//    9 -> 5 per wave-kc: ~123K cyc/CU, under the MFMA floor. vmcnt redone:
//    per kc [4 B][1 stage]; end-of-kc vmcnt(1) keeps kc+2 stage in flight.
//  - forward v5 / convert unchanged (forward's uniform-ds_read fix = s_load
//    path, isolated to next round).

typedef __attribute__((ext_vector_type(8))) short short8;
typedef __attribute__((ext_vector_type(4))) float f32x4;

union U16x8 {
  uint4 u;
  short8 s;
};

__device__ __forceinline__ uint16_t f2bf(float f) {
  uint32_t u = __float_as_uint(f);
  uint32_t lsb = (u >> 16) & 1u;
  u += 0x7FFFu + lsb;  // round-to-nearest-even
  return (uint16_t)(u >> 16);
}

// async global->LDS, 16B per lane: lane's data lands at lds_base + lane*16.
__device__ __forceinline__ void lds_load16(const uint4* gsrc, uint4* ldst) {
  __builtin_amdgcn_global_load_lds(
      (const __attribute__((address_space(1))) void*)gsrc,
      (__attribute__((address_space(3))) void*)ldst, 16, 0, 0);
}

// ---------------- convert: build swizzled bf16 fragments + fp32 transposes ----------------
// Fragment order (16x16x32 bf16 MFMA): lane = quad*16 + l15 holds 8 contiguous
// bf16 = 16 B; A-frag element (m=l15, k=quad*8+j); B-frag (n=l15, k=quad*8+j).
// A2swz[((r16*16 + kc)*64 + lane)*8 + j] = W2 [r16*16+l15][kc*32+quad*8+j]
// A3swz[  same index                   ] = W3T[r16*16+l15][kc*32+quad*8+j]
// B1swz[((kc*4 + jt)*64 + lane)*8 + j]  = W1T[jt*16+l15 ][kc*32+quad*8+j]
// B4swz[  same index                 ]  = W4 [jt*16+l15 ][kc*32+quad*8+j]
__global__ __launch_bounds__(256) void convert_kernel(
    const float* __restrict__ W1, const float* __restrict__ W2,
    const float* __restrict__ W3, const float* __restrict__ W4,
    uint16_t* __restrict__ A2swz, uint16_t* __restrict__ A3swz,
    uint16_t* __restrict__ B1swz, uint16_t* __restrict__ B4swz,
    float* __restrict__ W2Tf, float* __restrict__ W3Tf,
    float* __restrict__ W1Tf, float* __restrict__ W4Tf) {
  const int i = blockIdx.x * 256 + threadIdx.x;
  if (i < 262144) {  // A2swz
    const int e = i;
    const int f = e >> 3, j = e & 7;
    const int lane = f & 63, fk = f >> 6;
    const int kc = fk & 15, r16 = fk >> 4;
    const int l15 = lane & 15, quad = lane >> 4;
    const int row = r16 * 16 + l15, col = kc * 32 + quad * 8 + j;
    A2swz[e] = f2bf(W2[row * 512 + col]);
  } else if (i < 524288) {  // A3swz (= W3 transposed)
    const int e = i - 262144;
    const int f = e >> 3, j = e & 7;
    const int lane = f & 63, fk = f >> 6;
    const int kc = fk & 15, r16 = fk >> 4;
    const int l15 = lane & 15, quad = lane >> 4;
    const int row = r16 * 16 + l15, col = kc * 32 + quad * 8 + j;
    A3swz[e] = f2bf(W3[col * 512 + row]);
  } else if (i < 557056) {  // B1swz (= W1 transposed)
    const int e = i - 524288;
    const int f = e >> 3, j = e & 7;
    const int lane = f & 63, fk = f >> 6;
    const int kc = fk >> 2, jt = fk & 3;
    const int l15 = lane & 15, quad = lane >> 4;
    const int d = jt * 16 + l15, col = kc * 32 + quad * 8 + j;
    B1swz[e] = f2bf(W1[col * 64 + d]);
  } else if (i < 589824) {  // B4swz (= W4 row-major)
    const int e = i - 557056;
    const int f = e >> 3, j = e & 7;
    const int lane = f & 63, fk = f >> 6;
    const int kc = fk >> 2, jt = fk & 3;
    const int l15 = lane & 15, quad = lane >> 4;
    const int d = jt * 16 + l15, col = kc * 32 + quad * 8 + j;
    B4swz[e] = f2bf(W4[d * 512 + col]);
  } else if (i < 851968) {  // W2Tf [k][j]
    const int e = i - 589824;
    const int k = e >> 9, jj = e & 511;
    W2Tf[e] = W2[jj * 512 + k];
  } else if (i < 1114112) {  // W3Tf [k][j]
    const int e = i - 851968;
    const int k = e >> 9, jj = e & 511;
    W3Tf[e] = W3[jj * 512 + k];
  } else if (i < 1146880) {  // W1Tf [k][j], k<64
    const int e = i - 1114112;
    const int k = e >> 9, jj = e & 511;
    W1Tf[e] = W1[jj * 64 + k];
  } else if (i < 1179648) {  // W4Tf [k][d]
    const int e = i - 1146880;
    const int k = e >> 6, d = e & 63;
    W4Tf[e] = W4[d * 512 + k];
  }
}

// ---------------- forward v5 (fp32): W register double-buffer ----------------
// 512 blocks x 512 threads (8 waves); 4 samples/block -> 2 blocks/CU,
// 4 waves/SIMD. Thread t owns unit j=t for 4 samples.
// Hidden-layer inner loop: named wA[8]/wB[8] register double buffer; the 8
// loads for the NEXT half-step are issued before computing the current one.
// Mask: wave w covers units w*64..w*64+63 -> __ballot(a>0) = words 2w, 2w+1.
__device__ __forceinline__ void relu_store_mask4(
    float acc[4], float (*hdst)[4], uint32_t* __restrict__ mbase,
    int t, int lane, int wv) {
#pragma unroll
  for (int s = 0; s < 4; ++s) {
    const unsigned long long bal = __ballot(acc[s] > 0.f);
    if (lane == 0) {
      uint2 w2;
      w2.x = (uint32_t)bal;
      w2.y = (uint32_t)(bal >> 32);
      *(uint2*)(mbase + (size_t)s * 16 + 2 * wv) = w2;
    }
  }
  float4 r;
  r.x = acc[0] > 0.f ? acc[0] : 0.f;
  r.y = acc[1] > 0.f ? acc[1] : 0.f;
  r.z = acc[2] > 0.f ? acc[2] : 0.f;
  r.w = acc[3] > 0.f ? acc[3] : 0.f;
  *(float4*)&hdst[t][0] = r;
}

__device__ __forceinline__ void fwd_layer(
    const float* __restrict__ WT, const float* __restrict__ bias,
    const float (* __restrict__ src)[4], float (* __restrict__ dst)[4],
    uint32_t* __restrict__ mbase, int t, int lane, int wv, int K) {
  float acc[4];
  {
    const float bj = bias[t];
    acc[0] = bj; acc[1] = bj; acc[2] = bj; acc[3] = bj;
  }
  const float* Wp = WT + t;
  float wA[8], wB[8];
#pragma unroll
  for (int j = 0; j < 8; ++j) wA[j] = Wp[(size_t)j * 512];
#pragma unroll 1
  for (int kb = 0; kb < K; kb += 16) {
#pragma unroll
    for (int j = 0; j < 8; ++j) wB[j] = Wp[(size_t)(kb + 8 + j) * 512];
#pragma unroll
    for (int j = 0; j < 8; ++j) {
      const float4 h = *(const float4*)&src[kb + j][0];
      const float w = wA[j];
      acc[0] = fmaf(w, h.x, acc[0]); acc[1] = fmaf(w, h.y, acc[1]);
      acc[2] = fmaf(w, h.z, acc[2]); acc[3] = fmaf(w, h.w, acc[3]);
    }
    if (kb + 16 < K) {
#pragma unroll
      for (int j = 0; j < 8; ++j) wA[j] = Wp[(size_t)(kb + 16 + j) * 512];
    }
#pragma unroll
    for (int j = 0; j < 8; ++j) {
      const float4 h = *(const float4*)&src[kb + 8 + j][0];
      const float w = wB[j];
      acc[0] = fmaf(w, h.x, acc[0]); acc[1] = fmaf(w, h.y, acc[1]);
      acc[2] = fmaf(w, h.z, acc[2]); acc[3] = fmaf(w, h.w, acc[3]);
    }
  }
  relu_store_mask4(acc, dst, mbase, t, lane, wv);
}

__global__ __launch_bounds__(512) void forward_kernel(
    const float* __restrict__ x,
    const float* __restrict__ W1Tf, const float* __restrict__ b1,
    const float* __restrict__ W2Tf, const float* __restrict__ b2,
    const float* __restrict__ W3Tf, const float* __restrict__ b3,
    const float* __restrict__ W4Tf, const float* __restrict__ b4,
    uint32_t* __restrict__ m1p, uint32_t* __restrict__ m2p,
    uint32_t* __restrict__ m3p, float* __restrict__ out) {
  __shared__ float xs[64][4];   // [k][sample]
  __shared__ float hA[512][4];  // [unit][sample]
  __shared__ float hB[512][4];
  __shared__ float p4[4][2][64];  // layer-4 partials [sample][k-half][d]
  const int t = threadIdx.x;
  const int lane = t & 63, wv = t >> 6;
  const int b0 = blockIdx.x * 4;

  if (t < 256) {
    const int k = t >> 2, s = t & 3;  // 256 threads cover 4 samples x 64 k
    xs[k][s] = x[(size_t)(b0 + s) * 64 + k];
  }
  __syncthreads();

  fwd_layer(W1Tf, b1, xs, hA, m1p + (size_t)b0 * 16, t, lane, wv, 64);
  __syncthreads();
  fwd_layer(W2Tf, b2, hA, hB, m2p + (size_t)b0 * 16, t, lane, wv, 512);
  __syncthreads();
  fwd_layer(W3Tf, b3, hB, hA, m3p + (size_t)b0 * 16, t, lane, wv, 512);
  __syncthreads();

  // ---- layer 4 (K=512, D=64) + 0.5*||s||^2 : 8 waves, k-halves ----
  {
    const int s = wv & 3, hh = wv >> 2, d = lane;
    const int k0 = hh * 256;
    const float* Wp = W4Tf + (size_t)k0 * 64 + d;
    float ap[4] = {0.f, 0.f, 0.f, 0.f};
    float wA[8], wB[8];
#pragma unroll
    for (int j = 0; j < 8; ++j) wA[j] = Wp[(size_t)j * 64];
#pragma unroll 1
    for (int kb = 0; kb < 256; kb += 16) {
#pragma unroll
      for (int j = 0; j < 8; ++j) wB[j] = Wp[(size_t)(kb + 8 + j) * 64];
#pragma unroll
      for (int j = 0; j < 8; ++j)
        ap[j & 3] = fmaf(wA[j], hA[k0 + kb + j][s], ap[j & 3]);
      if (kb + 16 < 256) {
#pragma unroll
        for (int j = 0; j < 8; ++j) wA[j] = Wp[(size_t)(kb + 16 + j) * 64];
      }
#pragma unroll
      for (int j = 0; j < 8; ++j)
        ap[j & 3] = fmaf(wB[j], hA[k0 + kb + 8 + j][s], ap[j & 3]);
    }
    p4[s][hh][d] = (ap[0] + ap[1]) + (ap[2] + ap[3]);
  }
  __syncthreads();
  if (wv < 4) {
    const int s = wv, d = lane;
    const float a4 = p4[s][0][d] + p4[s][1][d] + b4[d];
    float sq = a4 * a4;
#pragma unroll
    for (int off = 32; off; off >>= 1) sq += __shfl_down(sq, off, 64);
    if (lane == 0) out[b0 + s] = 0.5f * sq;
  }
}

// ---------------- divergence v6: A in LDS, B from L1/global regs ----------------
// grid (512 sample-quads, 8 row-tiles of 64); block 512 = 8 waves.
// Wave wv: sLoc = wv&3 -> sample g4*4+sLoc; role = (wv<4 ? C : G).
// Per kc: wave stages ONE A-frag (slot wv: A2 it=wv&3 for C, A3 for G) via
// global_load_lds, 3 rotating buffers (stage kc+2 during kc).
// B-frags live in regs bfr[4], loaded per kc from B1swz/B4swz (128KB, L1-hot;
// identical addrs across same-role waves). Reload for kc+1 is issued right
// after the masked bf16 copy -> a full MFMA cluster (~300cyc) of latency cover.
// End-of-kc: vmcnt(1) (drains B(kc+1) + stage(kc+1), keeps stage(kc+2)) +
// raw s_barrier. LDS reads per wave-kc: 4 A b128 + 1 emask (was 9).
__device__ __forceinline__ void expand_mask(uint32_t byte8, uint32_t mk[4]) {
#pragma unroll
  for (int i = 0; i < 4; ++i) {
    mk[i] = (((byte8 >> (2 * i)) & 1u) ? 0x0000FFFFu : 0u) |
            (((byte8 >> (2 * i + 1)) & 1u) ? 0xFFFF0000u : 0u);
  }
}

__global__ __launch_bounds__(512, 4) void div_kernel(
    const uint4* __restrict__ A2swz, const uint4* __restrict__ A3swz,
    const uint4* __restrict__ B1swz, const uint4* __restrict__ B4swz,
    const uint32_t* __restrict__ m1p, const uint32_t* __restrict__ m2p,
    const uint32_t* __restrict__ m3p, float* __restrict__ out) {
  __shared__ uint4 sfrag[3][16][64];   // 48KB declared; slots 0..7 used/buf;
                                       // epilogue overlays 33.3KB of it.
  __shared__ uint4 emask[8][16][4];    // 8KB: [wave][kc][quad] expanded masks
  const int t = threadIdx.x;
  const int lane = t & 63, wv = t >> 6;
  const int quad = lane >> 4, l15 = lane & 15;
  const int g4 = blockIdx.x;
  const int rowB0 = blockIdx.y * 64;
  const int sLoc = wv & 3;
  const int b = g4 * 4 + sLoc;        // this wave's sample
  const int r16b = blockIdx.y * 4;    // row-16-tile base
  const bool isC = (wv < 4);

  const uint4* sbA = isC ? A2swz : A3swz;  // this wave's staged A source
  const uint4* sbB = isC ? B1swz : B4swz;  // this wave's B-frag source

  f32x4 acc[4][4];
#pragma unroll
  for (int it = 0; it < 4; ++it)
#pragma unroll
    for (int jt = 0; jt < 4; ++jt) acc[it][jt] = (f32x4){0.f, 0.f, 0.f, 0.f};

  // per-wave expanded-mask precompute: lane -> (kc = lane>>2, qd = lane&3).
  // C-waves use m1, G-waves use m3. Wave-private (in-wave lgkmcnt ordering).
  {
    const uint32_t* mp = (isC ? m1p : m3p) + (size_t)b * 16;
    const int kcl = lane >> 2, qd = lane & 3;
    const uint32_t word = mp[kcl];
    uint32_t mk[4];
    expand_mask((word >> (qd * 8)) & 0xFFu, mk);
    uint4 v;
    v.x = mk[0]; v.y = mk[1]; v.z = mk[2]; v.w = mk[3];
    emask[wv][kcl][qd] = v;
  }

  // stageA(buf, kc): wave wv stages its single A slot (it = wv&3)
  auto stageA = [&](int sbuf, int kc) {
    const size_t off = (size_t)((r16b + (wv & 3)) * 16 + kc) * 64 + lane;
    lds_load16(sbA + off, &sfrag[sbuf][wv][0]);
  };

  uint4 bfr[4];
  // prologue: S(0)[1], B(0)[4], S(1)[1] -> vmcnt(1) drains S0+B0, keeps S1.
  stageA(0, 0);
#pragma unroll
  for (int jt = 0; jt < 4; ++jt) bfr[jt] = sbB[(size_t)jt * 64 + lane];
  stageA(1, 1);
  __builtin_amdgcn_sched_barrier(0);
  asm volatile("s_waitcnt vmcnt(1)" ::: "memory");
  __builtin_amdgcn_s_barrier();
  __builtin_amdgcn_sched_barrier(0);

  const int base = isC ? 0 : 4;

#pragma unroll 1
  for (int kc = 0; kc < 16; ++kc) {
    const int rb = kc % 3;

    const uint4 mku = emask[wv][kc][quad];  // broadcast ds_read_b128

    // masked bf16 B operands from regs (loaded last kc)
    short8 bf[4];
#pragma unroll
    for (int jt = 0; jt < 4; ++jt) {
      U16x8 uu;
      uu.u = bfr[jt];
      uu.u.x &= mku.x; uu.u.y &= mku.y; uu.u.z &= mku.z; uu.u.w &= mku.w;
      bf[jt] = uu.s;
    }
    // issue next-kc B loads now (covered by the MFMA cluster below)
    if (kc < 15) {
#pragma unroll
      for (int jt = 0; jt < 4; ++jt)
        bfr[jt] = sbB[(size_t)((kc + 1) * 4 + jt) * 64 + lane];
    }
    // stage A for kc+2
    if (kc < 14) stageA((kc + 2) % 3, kc + 2);

    uint4 a[4];
#pragma unroll
    for (int q = 0; q < 4; ++q) a[q] = sfrag[rb][base + q][lane];

#pragma unroll
    for (int it = 0; it < 4; ++it) {
      U16x8 ua;
      ua.u = a[it];
      const short8 af = ua.s;
#pragma unroll
      for (int jt = 0; jt < 4; ++jt)
        acc[it][jt] = __builtin_amdgcn_mfma_f32_16x16x32_bf16(af, bf[jt], acc[it][jt], 0, 0, 0);
    }

    // counted wait: drain B(kc+1) + stage(kc+1); keep stage(kc+2) in flight.
    if (kc < 14) {
      asm volatile("s_waitcnt vmcnt(1)" ::: "memory");
    } else if (kc == 14) {
      asm volatile("s_waitcnt vmcnt(0)" ::: "memory");  // drain last stage + B
    }
    if (kc < 15) {
      __builtin_amdgcn_s_barrier();
      __builtin_amdgcn_sched_barrier(0);  // no hoisting across the barrier
    }
  }

  // ---- epilogue: exchange C via LDS (2 halves of 32 rows), G applies m2 ----
  // C/D layout: row = it*16 + quad*4 + reg, col = jt*16 + l15.
  __syncthreads();  // all sfrag reads done; safe to overlay
  float* cxf = (float*)&sfrag[0][0][0];  // [sample][32 rows][stride 65]
  float dsum = 0.f;
  const uint32_t* m2w = m2p + (size_t)b * 16;
#pragma unroll
  for (int h = 0; h < 2; ++h) {
    if (isC) {
#pragma unroll
      for (int ith = 0; ith < 2; ++ith)
#pragma unroll
        for (int jt = 0; jt < 4; ++jt) {
          float* crow = &cxf[((size_t)sLoc * 32 + ith * 16 + quad * 4) * 65 +
                             jt * 16 + l15];
          crow[0 * 65] = acc[h * 2 + ith][jt][0];
          crow[1 * 65] = acc[h * 2 + ith][jt][1];
          crow[2 * 65] = acc[h * 2 + ith][jt][2];
          crow[3 * 65] = acc[h * 2 + ith][jt][3];
        }
    }
    __syncthreads();
    if (!isC) {
#pragma unroll
      for (int ith = 0; ith < 2; ++ith) {
        const int it = h * 2 + ith;
        const int rloc = it * 16 + quad * 4;
        const uint32_t md = m2w[(rowB0 + rloc) >> 5];
        const uint32_t bits = (md >> (rloc & 31)) & 0xFu;
        const float w0 = (bits & 1u) ? 1.f : 0.f;
        const float w1 = (bits & 2u) ? 1.f : 0.f;
        const float w2 = (bits & 4u) ? 1.f : 0.f;
        const float w3 = (bits & 8u) ? 1.f : 0.f;
#pragma unroll
        for (int jt = 0; jt < 4; ++jt) {
          const float* crow = &cxf[((size_t)sLoc * 32 + ith * 16 + quad * 4) * 65 +
                                   jt * 16 + l15];
          dsum = fmaf(w0, acc[it][jt][0] * crow[0 * 65], dsum);
          dsum = fmaf(w1, acc[it][jt][1] * crow[1 * 65], dsum);
          dsum = fmaf(w2, acc[it][jt][2] * crow[2 * 65], dsum);
          dsum = fmaf(w3, acc[it][jt][3] * crow[3 * 65], dsum);
        }
      }
    }
    __syncthreads();
  }
  if (!isC) {
#pragma unroll
    for (int off = 32; off; off >>= 1) dsum += __shfl_down(dsum, off, 64);
    if (lane == 0) atomicAdd(out + b, dsum);
  }
}

extern "C" void kernel_launch(void* const* d_in, const int* in_sizes, int n_in,
                              void* d_out, int out_size, void* d_ws, size_t ws_size,
                              hipStream_t stream) {
  const float* x  = (const float*)d_in[0];
  const float* W1 = (const float*)d_in[1];
  const float* b1 = (const float*)d_in[2];
  const float* W2 = (const float*)d_in[3];
  const float* b2 = (const float*)d_in[4];
  const float* W3 = (const float*)d_in[5];
  const float* b3 = (const float*)d_in[6];
  const float* W4 = (const float*)d_in[7];
  const float* b4 = (const float*)d_in[8];
  float* out = (float*)d_out;

  // workspace layout (bytes), total 3,932,160:
  char* ws = (char*)d_ws;
  uint16_t* A2swz = (uint16_t*)(ws + 0);        // 524288
  uint16_t* A3swz = (uint16_t*)(ws + 524288);   // 524288
  uint16_t* B1swz = (uint16_t*)(ws + 1048576);  // 65536
  uint16_t* B4swz = (uint16_t*)(ws + 1114112);  // 65536
  float*    W2Tf  = (float*)(ws + 1179648);     // 1048576
  float*    W3Tf  = (float*)(ws + 2228224);     // 1048576
  float*    W1Tf  = (float*)(ws + 3276800);     // 131072
  float*    W4Tf  = (float*)(ws + 3407872);     // 131072
  uint32_t* m1p   = (uint32_t*)(ws + 3538944);  // 131072 (2048 x 512 bits)
  uint32_t* m2p   = (uint32_t*)(ws + 3670016);  // 131072
  uint32_t* m3p   = (uint32_t*)(ws + 3801088);  // 131072
  if (ws_size < 3932160) return;

  convert_kernel<<<4608, 256, 0, stream>>>(W1, W2, W3, W4,
                                           A2swz, A3swz, B1swz, B4swz,
                                           W2Tf, W3Tf, W1Tf, W4Tf);
  forward_kernel<<<512, 512, 0, stream>>>(x, W1Tf, b1, W2Tf, b2, W3Tf, b3,
                                          W4Tf, b4, m1p, m2p, m3p, out);
  div_kernel<<<dim3(512, 8), 512, 0, stream>>>((const uint4*)A2swz,
                                               (const uint4*)A3swz,
                                               (const uint4*)B1swz,
                                               (const uint4*)B4swz,
                                               m1p, m2p, m3p, out);
}